// Round 14
// baseline (19.590 us; speedup 1.0000x reference)
//
#include <hip/hip_runtime.h>

// MakeCutouts: 32 random crops (sz in [224,511]) of a [2,3,512,512] fp32
// image, each adaptive-avg-pooled (PyTorch semantics) to 224x224.
// Output: [32*2, 3, 224, 224] fp32.
//
// R13 (16.6us) = R4 body + balanced XCD-affine row chunks (confirmed the
// cold-read-flood theory: -4.3us). R14 = single-variable A/B: drop the
// nontemporal hint on output stores. Rationale: nt was chosen in R1 to keep
// the 6.3MB input L2-resident, but with the XCD mapping each XCD's input
// working set is ~0.8MB << 4MiB L2; meanwhile nt (no-allocate/evict-first)
// plausibly caps TCC write-combining - the harness's plain-store fills
// sustain 6.6 TB/s vs our 4.3 TB/s steady. If nt was the throttle:
// 16.6 -> ~14. If null/regression: nt returns and we're near the floor.

constexpr int CUT   = 224;
constexpr int BC    = 6;          // B*C = 2*3
constexpr int HH    = 512;
constexpr int WW    = 512;
constexpr int PIX   = CUT * CUT;  // 50176
constexpr int PLANE = HH * WW;
constexpr int CHUNK = CUT / 8;    // 28 rows per XCD per cutout

__global__ __launch_bounds__(256) void cutout_kernel(
    const float* __restrict__ in,     // [6, 512, 512] planes
    const int*   __restrict__ sizes,  // [32]
    const int*   __restrict__ offx,   // [32]
    const int*   __restrict__ offy,   // [32]
    float*       __restrict__ out)    // [32, 6, 224, 224] flat
{
    __shared__ float2 vsum[3][WW];    // [plane-pair][crop col] = 12 KB

    // Balanced XCD-affine decode: bid%8 = XCD (round-robin dispatch),
    // XCD x gets rows 28x..28x+27 of every cutout, r-major within a cutout.
    const int bid = blockIdx.x;
    const int xcd = bid & 7;
    const int idx = bid >> 3;          // 0..895 = n*28 + r
    const int n   = idx / CHUNK;       // cutout
    const int r0  = idx - n * CHUNK;   // 0..27
    const int i   = xcd * CHUNK + r0;  // output row

    const int t = threadIdx.x;

    const int sz = sizes[n];          // uniform -> scalar
    const int oy = offy[n];
    const int ox = offx[n];

    const int sy = (i * sz) / CUT;                        // uniform
    const int dy = ((i + 1) * sz + CUT - 1) / CUT - sy;   // 1..4, uniform

    const float* __restrict__ base = in + (oy + sy) * WW + ox;
    const bool c0 = t < sz;           // sz >= 224; only lanes 224..255 can fail
    const bool c1 = t + 256 < sz;

    // Phase 1: vertical sums over dy rows, cols t and t+256 (crop-relative).
    float a0=0.f,a1=0.f,a2=0.f,a3=0.f,a4=0.f,a5=0.f;  // col t
    float b0=0.f,b1=0.f,b2=0.f,b3=0.f,b4=0.f,b5=0.f;  // col t+256
    for (int r = 0; r < dy; ++r) {    // uniform trip count
        const float* __restrict__ rp = base + r * WW;
        if (c0) {
            a0 += rp[0*PLANE + t]; a1 += rp[1*PLANE + t]; a2 += rp[2*PLANE + t];
            a3 += rp[3*PLANE + t]; a4 += rp[4*PLANE + t]; a5 += rp[5*PLANE + t];
        }
        if (c1) {
            const int u = t + 256;
            b0 += rp[0*PLANE + u]; b1 += rp[1*PLANE + u]; b2 += rp[2*PLANE + u];
            b3 += rp[3*PLANE + u]; b4 += rp[4*PLANE + u]; b5 += rp[5*PLANE + u];
        }
    }
    if (c0) {
        vsum[0][t] = make_float2(a0, a1);
        vsum[1][t] = make_float2(a2, a3);
        vsum[2][t] = make_float2(a4, a5);
    }
    if (c1) {
        const int u = t + 256;
        vsum[0][u] = make_float2(b0, b1);
        vsum[1][u] = make_float2(b2, b3);
        vsum[2][u] = make_float2(b4, b5);
    }
    __syncthreads();

    // Phase 2: horizontal pooling from LDS, 4 predicated taps (dx in 1..4).
    if (t < CUT) {
        const int sx = (t * sz) / CUT;                        // crop-relative
        const int dx = ((t + 1) * sz + CUT - 1) / CUT - sx;   // 1..4
        const int x1 = sx + (dx > 1 ? 1 : 0);                 // clamped taps
        const int x2 = x1 + (dx > 2 ? 1 : 0);
        const int x3 = x2 + (dx > 3 ? 1 : 0);
        const float w1 = dx > 1 ? 1.f : 0.f;
        const float w2 = dx > 2 ? 1.f : 0.f;
        const float w3 = dx > 3 ? 1.f : 0.f;
        const float rr = __builtin_amdgcn_rcpf((float)(dy * dx));

        float* o = out + (size_t)n * BC * PIX + i * CUT + t;
        #pragma unroll
        for (int pr = 0; pr < 3; ++pr) {
            const float2 v0 = vsum[pr][sx];
            const float2 v1 = vsum[pr][x1];
            const float2 v2 = vsum[pr][x2];
            const float2 v3 = vsum[pr][x3];
            const float se = v0.x + w1 * v1.x + w2 * v2.x + w3 * v3.x;
            const float so = v0.y + w1 * v1.y + w2 * v2.y + w3 * v3.y;
            o[(2 * pr    ) * PIX] = se * rr;   // plain stores (A/B vs nt)
            o[(2 * pr + 1) * PIX] = so * rr;
        }
    }
}

extern "C" void kernel_launch(void* const* d_in, const int* in_sizes, int n_in,
                              void* d_out, int out_size, void* d_ws, size_t ws_size,
                              hipStream_t stream) {
    const float* in    = (const float*)d_in[0];
    const int*   sizes = (const int*)d_in[1];
    const int*   offx  = (const int*)d_in[2];
    const int*   offy  = (const int*)d_in[3];
    float*       out   = (float*)d_out;

    cutout_kernel<<<dim3(CUT * 32), dim3(256), 0, stream>>>(
        in, sizes, offx, offy, out);
}

// Round 15
// 17.008 us; speedup vs baseline: 1.1518x; 1.1518x over previous
//
#include <hip/hip_runtime.h>

// MakeCutouts: 32 random crops (sz in [224,511]) of a [2,3,512,512] fp32
// image, each adaptive-avg-pooled (PyTorch semantics) to 224x224.
// Output: [32*2, 3, 224, 224] fp32.
//
// R14 verdict: plain stores 19.6 vs nt 16.6 -> nt stores KEEP (they protect
// the L2 working set from the 38MB write stream). R15 = R13 (best, 16.6us)
// + the one remaining measured inefficiency: phase-2 LDS tap reads are 8B
// elements -> even banks only -> ~4-way conflict (940K cyc/iter, ~1us).
// Fix: gap-padded index c -> c + (c>>4) (8B gap per 16 cols, 3x544 float2):
// tap-read bank ~ 4.86*lane mod 32, no small period -> ~2-way (free, m136).

constexpr int CUT   = 224;
constexpr int BC    = 6;          // B*C = 2*3
constexpr int HH    = 512;
constexpr int WW    = 512;
constexpr int PIX   = CUT * CUT;  // 50176
constexpr int PLANE = HH * WW;
constexpr int CHUNK = CUT / 8;    // 28 rows per XCD per cutout
constexpr int PADW  = WW + (WW >> 4);   // 544 padded cols

__device__ __forceinline__ int padix(int c) { return c + (c >> 4); }

__global__ __launch_bounds__(256) void cutout_kernel(
    const float* __restrict__ in,     // [6, 512, 512] planes
    const int*   __restrict__ sizes,  // [32]
    const int*   __restrict__ offx,   // [32]
    const int*   __restrict__ offy,   // [32]
    float*       __restrict__ out)    // [32, 6, 224, 224] flat
{
    __shared__ float2 vsum[3][PADW];  // [plane-pair][padded crop col] ~12.8 KB

    // Balanced XCD-affine decode: bid%8 = XCD (round-robin dispatch),
    // XCD x gets rows 28x..28x+27 of every cutout, r-major within a cutout.
    const int bid = blockIdx.x;
    const int xcd = bid & 7;
    const int idx = bid >> 3;          // 0..895 = n*28 + r
    const int n   = idx / CHUNK;       // cutout
    const int r0  = idx - n * CHUNK;   // 0..27
    const int i   = xcd * CHUNK + r0;  // output row

    const int t = threadIdx.x;

    const int sz = sizes[n];          // uniform -> scalar
    const int oy = offy[n];
    const int ox = offx[n];

    const int sy = (i * sz) / CUT;                        // uniform
    const int dy = ((i + 1) * sz + CUT - 1) / CUT - sy;   // 1..4, uniform

    const float* __restrict__ base = in + (oy + sy) * WW + ox;
    const bool c0 = t < sz;           // sz >= 224; only lanes 224..255 can fail
    const bool c1 = t + 256 < sz;

    // Phase 1: vertical sums over dy rows, cols t and t+256 (crop-relative).
    float a0=0.f,a1=0.f,a2=0.f,a3=0.f,a4=0.f,a5=0.f;  // col t
    float b0=0.f,b1=0.f,b2=0.f,b3=0.f,b4=0.f,b5=0.f;  // col t+256
    for (int r = 0; r < dy; ++r) {    // uniform trip count
        const float* __restrict__ rp = base + r * WW;
        if (c0) {
            a0 += rp[0*PLANE + t]; a1 += rp[1*PLANE + t]; a2 += rp[2*PLANE + t];
            a3 += rp[3*PLANE + t]; a4 += rp[4*PLANE + t]; a5 += rp[5*PLANE + t];
        }
        if (c1) {
            const int u = t + 256;
            b0 += rp[0*PLANE + u]; b1 += rp[1*PLANE + u]; b2 += rp[2*PLANE + u];
            b3 += rp[3*PLANE + u]; b4 += rp[4*PLANE + u]; b5 += rp[5*PLANE + u];
        }
    }
    if (c0) {
        const int pt = padix(t);
        vsum[0][pt] = make_float2(a0, a1);
        vsum[1][pt] = make_float2(a2, a3);
        vsum[2][pt] = make_float2(a4, a5);
    }
    if (c1) {
        const int pu = padix(t + 256);
        vsum[0][pu] = make_float2(b0, b1);
        vsum[1][pu] = make_float2(b2, b3);
        vsum[2][pu] = make_float2(b4, b5);
    }
    __syncthreads();

    // Phase 2: horizontal pooling from LDS, 4 predicated taps (dx in 1..4).
    if (t < CUT) {
        const int sx = (t * sz) / CUT;                        // crop-relative
        const int dx = ((t + 1) * sz + CUT - 1) / CUT - sx;   // 1..4
        const int x1 = sx + (dx > 1 ? 1 : 0);                 // clamped taps
        const int x2 = x1 + (dx > 2 ? 1 : 0);
        const int x3 = x2 + (dx > 3 ? 1 : 0);
        const int p0 = padix(sx), p1 = padix(x1), p2 = padix(x2), p3 = padix(x3);
        const float w1 = dx > 1 ? 1.f : 0.f;
        const float w2 = dx > 2 ? 1.f : 0.f;
        const float w3 = dx > 3 ? 1.f : 0.f;
        const float rr = __builtin_amdgcn_rcpf((float)(dy * dx));

        float* o = out + (size_t)n * BC * PIX + i * CUT + t;
        #pragma unroll
        for (int pr = 0; pr < 3; ++pr) {
            const float2 v0 = vsum[pr][p0];
            const float2 v1 = vsum[pr][p1];
            const float2 v2 = vsum[pr][p2];
            const float2 v3 = vsum[pr][p3];
            const float se = v0.x + w1 * v1.x + w2 * v2.x + w3 * v3.x;
            const float so = v0.y + w1 * v1.y + w2 * v2.y + w3 * v3.y;
            __builtin_nontemporal_store(se * rr, o + (2 * pr    ) * PIX);
            __builtin_nontemporal_store(so * rr, o + (2 * pr + 1) * PIX);
        }
    }
}

extern "C" void kernel_launch(void* const* d_in, const int* in_sizes, int n_in,
                              void* d_out, int out_size, void* d_ws, size_t ws_size,
                              hipStream_t stream) {
    const float* in    = (const float*)d_in[0];
    const int*   sizes = (const int*)d_in[1];
    const int*   offx  = (const int*)d_in[2];
    const int*   offy  = (const int*)d_in[3];
    float*       out   = (float*)d_out;

    cutout_kernel<<<dim3(CUT * 32), dim3(256), 0, stream>>>(
        in, sizes, offx, offy, out);
}